// Round 11
// baseline (96.281 us; speedup 1.0000x reference)
//
#include <hip/hip_runtime.h>
#include <math.h>

// B=16384, S=64, V=25, E=64, H=64, 4H=256, C=3
// gates^T[gunit][brow] = W_fused[gunit][k] @ x^T[k][brow] via mfma_f32_16x16x32_bf16.
// A = weights (VGPR-stationary), B = activations (msg from global, h from LDS).
// K = 3 chunks of 32: ch0 = msg k=0..24 (+k=25 bias row, 1.0 in B), ch1/2 = h bf16.
// Weights pre-scaled: i,f,o rows by -log2(e); g rows by +2*log2(e) -> no runtime muls.
// Block = 4 waves (256 thr) = 16 batch rows; wave cg owns h-units [16cg,16cg+16).
//
// R10 changes vs R6 (the 112us kernel):
//  * __syncthreads() -> "s_waitcnt lgkmcnt(0); s_barrier": h-exchange only needs
//    LDS drained. Stock __syncthreads emits vmcnt(0) too, which drained the msg
//    prefetch at EVERY step barrier (HBM latency ~900cy exposed per step).
//  * msg prefetch depth 2 (raw f32 regs, cvt_pk at consumption) so ~2 compute
//    steps cover HBM latency; vmcnt waits land only at the consumption point.

using bf16x8 = __attribute__((ext_vector_type(8))) short;
using f32x4  = __attribute__((ext_vector_type(4))) float;

union U16B { uint4 u; bf16x8 v; };

#define KE  1.4426950408889634f
#define K2E 2.8853900817779268f

__device__ __forceinline__ unsigned short f2bf(float x) {
    unsigned int u = __float_as_uint(x);
    u += 0x7FFFu + ((u >> 16) & 1u);           // RNE
    return (unsigned short)(u >> 16);
}
__device__ __forceinline__ float bf2f(unsigned short h) {
    return __uint_as_float(((unsigned int)h) << 16);
}

// A-fragment layout for 16x16x32: lane holds A[row=lane&15][k=(lane>>4)*8+j], j=0..7.
// wfrag[((ch*16+gt)*64+lane)*8+j]: tile gt covers gunits [16gt,16gt+16).
// ch0: combT[gunit][k] = sum_e emb[k][e]*Wih[gunit][e] (k<25), k==25 -> bias; ch1/2: Whh[gunit][k].
// All values pre-scaled by s(gate): gate=gunit>>6 (i,f,g,o); s = (gate==2)? +K2E : -KE.
__global__ void prep_kernel(const float* __restrict__ emb,
                            const float* __restrict__ Wih,
                            const float* __restrict__ Whh,
                            const float* __restrict__ bih,
                            const float* __restrict__ bhh,
                            unsigned short* __restrict__ wfrag) {
    const int b = blockIdx.x, tid = threadIdx.x;
    const int ch = b >> 4, gt = b & 15;
    const int lane = tid >> 3, j = tid & 7;
    const int kloc = (lane >> 4) * 8 + j;       // 0..31
    const int gunit = 16 * gt + (lane & 15);    // 0..255
    float v = 0.f;
    if (ch == 0) {
        if (kloc < 25) {
            const float* ep = emb + kloc * 64;
            const float* wp = Wih + gunit * 64;
            float s = 0.f;
            #pragma unroll
            for (int e = 0; e < 64; ++e) s = fmaf(ep[e], wp[e], s);
            v = s;
        } else if (kloc == 25) {
            v = bih[gunit] + bhh[gunit];        // bias row
        }
    } else {
        v = Whh[gunit * 64 + (ch - 1) * 32 + kloc];
    }
    const int gate = gunit >> 6;
    const float s = (gate == 2) ? K2E : -KE;
    wfrag[((ch * 16 + gt) * 64 + lane) * 8 + j] = f2bf(s * v);
}

#define CVTPK(D, A, B_)                                                      \
    asm("v_cvt_pk_bf16_f32 %0, %1, %2" : "=v"(D) : "v"(A), "v"(B_));

// LDS-only barrier: h exchange needs lgkmcnt drained, NOT vmcnt — msg
// prefetch loads stay in flight across the barrier.
#define BARRIER()                                                            \
    asm volatile("s_waitcnt lgkmcnt(0)\n\ts_barrier" ::: "memory");

// Load step SS's msg slice as raw f32 (8 regs); no conversion here so the
// compiler's vmcnt wait lands at the consumption (CONVMSG), 2 steps later.
#define LOADMSG(DST, SS)                                                     \
    {                                                                        \
        const float* p_ = mrow + (SS) * 25 + kq;                             \
        if (kq < 24) {                                                       \
            _Pragma("unroll") for (int j = 0; j < 8; ++j) DST[j] = p_[j];    \
        } else {                                                             \
            DST[0] = p_[0]; DST[1] = 1.0f;   /* bias row k=25 */             \
            _Pragma("unroll") for (int j = 2; j < 8; ++j) DST[j] = 0.f;      \
        }                                                                    \
    }

#define CONVMSG(MB, MF)                                                      \
    {                                                                        \
        CVTPK(MB.u.x, MF[0], MF[1]) CVTPK(MB.u.y, MF[2], MF[3])              \
        CVTPK(MB.u.z, MF[4], MF[5]) CVTPK(MB.u.w, MF[6], MF[7])              \
    }

// MF: float[8] buffer holding step S's msg (loaded 2 steps ago); after
// consumption it is refilled with step S+2's msg.
#define STEP(S, CURB, NXTB, MF)                                              \
    {                                                                        \
        U16B mc_;                                                            \
        CONVMSG(mc_, MF)                                                     \
        if ((S) < 62) LOADMSG(MF, (S) + 2)                                   \
        bf16x8 bh[2];                                                        \
        _Pragma("unroll") for (int ch = 0; ch < 2; ++ch) {                   \
            int off_ = (l16 * 128 + ch * 64 + lq * 16) ^ swz;                \
            bh[ch] = *(const bf16x8*)((CURB) + off_);                        \
        }                                                                    \
        f32x4 acc[4];                                                        \
        _Pragma("unroll") for (int i = 0; i < 4; ++i)                        \
            acc[i] = (f32x4){0.f, 0.f, 0.f, 0.f};                            \
        _Pragma("unroll") for (int i = 0; i < 4; ++i)                        \
            acc[i] = __builtin_amdgcn_mfma_f32_16x16x32_bf16(                \
                w[0][i], mc_.v, acc[i], 0, 0, 0);                            \
        _Pragma("unroll") for (int ch = 0; ch < 2; ++ch)                     \
            _Pragma("unroll") for (int i = 0; i < 4; ++i)                    \
                acc[i] = __builtin_amdgcn_mfma_f32_16x16x32_bf16(            \
                    w[1 + ch][i], bh[ch], acc[i], 0, 0, 0);                  \
        float hn[4];                                                         \
        _Pragma("unroll") for (int q = 0; q < 4; ++q) {                      \
            float ai = acc[0][q], af = acc[1][q];                            \
            float ag = acc[2][q], ao = acc[3][q];                            \
            float ti = __builtin_amdgcn_exp2f(ai);                           \
            float tf = __builtin_amdgcn_exp2f(af);                           \
            float to = __builtin_amdgcn_exp2f(ao);                           \
            float tg = __builtin_amdgcn_exp2f(-fabsf(ag));                   \
            float ig = (1.f - tg) *                                          \
                __builtin_amdgcn_rcpf((1.f + ti) * (1.f + tg));              \
            ig = copysignf(ig, ag);                                          \
            float fg = __builtin_amdgcn_rcpf(1.f + tf);                      \
            float cn = fmaf(fg, c[q], ig);                                   \
            c[q] = cn;                                                       \
            float tc = __builtin_amdgcn_exp2f(-fabsf(K2E * cn));             \
            float ot = (1.f - tc) *                                          \
                __builtin_amdgcn_rcpf((1.f + to) * (1.f + tc));              \
            hn[q] = copysignf(ot, cn);                                       \
        }                                                                    \
        unsigned r01_, r23_;                                                 \
        CVTPK(r01_, hn[0], hn[1]) CVTPK(r23_, hn[2], hn[3])                  \
        *(uint2*)((NXTB) + offw) = make_uint2(r01_, r23_);                   \
        BARRIER()                                                            \
    }

__global__ __launch_bounds__(256, 4) void lstm_mfma(
    const float* __restrict__ msgs,
    const unsigned short* __restrict__ wfrag,
    const float* __restrict__ fcw,
    const float* __restrict__ fcb,
    float* __restrict__ out)
{
    // double-buffered h: buf = h[16 brows][64 units] bf16 = 2KB, x2
    __shared__ __align__(16) char lds[4096];

    const int tid  = threadIdx.x;
    const int lane = tid & 63;
    const int cg   = __builtin_amdgcn_readfirstlane(tid >> 6); // 0..3 (SGPR)
    const int l16  = lane & 15;                 // batch row within tile
    const int lq   = lane >> 4;                 // k-quad / unit-quad
    const int row0 = blockIdx.x * 16;
    const int kq   = lq * 8;                    // k base within chunk

    // weight A-fragments in VGPRs: gate i -> tile 4i+cg, 3 chunks (48 regs)
    bf16x8 w[3][4];
    #pragma unroll
    for (int ch = 0; ch < 3; ++ch)
        #pragma unroll
        for (int i = 0; i < 4; ++i)
            w[ch][i] = *(const bf16x8*)(wfrag + ((ch * 16 + 4 * i + cg) * 64 + lane) * 8);

    // zero h buffer 0 (2KB)
    for (int idx = tid; idx < 512; idx += 256) ((unsigned int*)lds)[idx] = 0u;

    float c[4] = {0.f, 0.f, 0.f, 0.f};

    const float* mrow = msgs + (long)(row0 + l16) * 1600;
    const int swz  = (l16 & 7) << 4;
    // this thread writes h[brow=l16][units 16cg+4lq .. +3] -> 8B
    const int offw = (l16 * 128 + cg * 32 + lq * 8) ^ swz;

    float mfA[8], mfB[8];
    LOADMSG(mfA, 0)
    LOADMSG(mfB, 1)
    __syncthreads();   // one-time full barrier (zeroed LDS visible)

    char* b0 = (char*)lds;
    char* b1 = b0 + 2048;
    for (int s2 = 0; s2 < 64; s2 += 2) {
        STEP(s2,     b0, b1, mfA)
        STEP(s2 + 1, b1, b0, mfB)
    }

    // final h in b0 as h[brow][unit]. FC epilogue: thread -> (row, class)
    if (tid < 64) {
        const int r = tid >> 2, cls = tid & 3;
        if (cls < 3) {
            float a = fcb[cls];
            const int sw = (r & 7) << 4;
            #pragma unroll
            for (int u = 0; u < 64; ++u) {
                int off = (r * 128 + u * 2) ^ sw;
                float hv = bf2f(*(const unsigned short*)(b0 + off));
                a = fmaf(hv, fcw[cls * 64 + u], a);
            }
            out[(row0 + r) * 3 + cls] = a;
        }
    }
}

extern "C" void kernel_launch(void* const* d_in, const int* in_sizes, int n_in,
                              void* d_out, int out_size, void* d_ws, size_t ws_size,
                              hipStream_t stream) {
    const float* msgs = (const float*)d_in[0];
    const float* emb  = (const float*)d_in[1];
    const float* Wih  = (const float*)d_in[2];
    const float* Whh  = (const float*)d_in[3];
    const float* bih  = (const float*)d_in[4];
    const float* bhh  = (const float*)d_in[5];
    const float* fcw  = (const float*)d_in[6];
    const float* fcb  = (const float*)d_in[7];
    float* out = (float*)d_out;

    // ws: wfrag bf16[3*16*64*8] = 49152 B
    unsigned short* wfrag = (unsigned short*)d_ws;

    prep_kernel<<<48, 512, 0, stream>>>(emb, Wih, Whh, bih, bhh, wfrag);
    lstm_mfma<<<16384 / 16, 256, 0, stream>>>(msgs, wfrag, fcw, fcb, out);
}

// Round 12
// 92.296 us; speedup vs baseline: 1.0432x; 1.0432x over previous
//
#include <hip/hip_runtime.h>
#include <math.h>

// B=16384, S=64, V=25, E=64, H=64, 4H=256, C=3
// gates^T[gunit][brow] = W_fused[gunit][k] @ x^T[k][brow] via mfma_f32_16x16x32_bf16.
// A = weights (VGPR-stationary), B = activations (msg from global, h from LDS).
// K = 3 chunks of 32: ch0 = msg k=0..24 (+k=25 bias row, 1.0 in B), ch1/2 = h bf16.
// Weights pre-scaled: i,f,o rows by -log2(e); g rows by +2*log2(e).
// Block = 4 waves (256 thr) = 16 batch rows; wave cg owns h-units [16cg,16cg+16).
//
// R12 changes vs R10 (96us):
//  * persistent zero f32x4 as the C-operand of each chain's first MFMA
//    (kills 16 v_mov zero-inits per step)
//  * single-rcp cell: cn = [c*P + s(1-tg)(1+tf)] * rcp(P*(1+tf)),
//    P=(1+ti)(1+tg)  -> 5 exp2 + 2 rcp per cell (was +3 rcp)
//  * activation arithmetic on f32x2 pairs -> v_pk_{add,mul,fma}_f32
//  * h ds_reads issued first after the barrier; msg pointer-increment

using bf16x8 = __attribute__((ext_vector_type(8))) short;
using f32x4  = __attribute__((ext_vector_type(4))) float;
using f32x2  = __attribute__((ext_vector_type(2))) float;

union U16B { uint4 u; bf16x8 v; };

#define KE  1.4426950408889634f
#define K2E 2.8853900817779268f

__device__ __forceinline__ unsigned short f2bf(float x) {
    unsigned int u = __float_as_uint(x);
    u += 0x7FFFu + ((u >> 16) & 1u);           // RNE
    return (unsigned short)(u >> 16);
}
__device__ __forceinline__ float bf2f(unsigned short h) {
    return __uint_as_float(((unsigned int)h) << 16);
}

// A-fragment layout for 16x16x32: lane holds A[row=lane&15][k=(lane>>4)*8+j], j=0..7.
// wfrag[((ch*16+gt)*64+lane)*8+j]: tile gt covers gunits [16gt,16gt+16).
// ch0: combT[gunit][k] (k<25), k==25 -> bias; ch1/2: Whh[gunit][k].
// All values pre-scaled by s(gate): gate=gunit>>6 (i,f,g,o); s = (gate==2)? +K2E : -KE.
__global__ void prep_kernel(const float* __restrict__ emb,
                            const float* __restrict__ Wih,
                            const float* __restrict__ Whh,
                            const float* __restrict__ bih,
                            const float* __restrict__ bhh,
                            unsigned short* __restrict__ wfrag) {
    const int b = blockIdx.x, tid = threadIdx.x;
    const int ch = b >> 4, gt = b & 15;
    const int lane = tid >> 3, j = tid & 7;
    const int kloc = (lane >> 4) * 8 + j;       // 0..31
    const int gunit = 16 * gt + (lane & 15);    // 0..255
    float v = 0.f;
    if (ch == 0) {
        if (kloc < 25) {
            const float* ep = emb + kloc * 64;
            const float* wp = Wih + gunit * 64;
            float s = 0.f;
            #pragma unroll
            for (int e = 0; e < 64; ++e) s = fmaf(ep[e], wp[e], s);
            v = s;
        } else if (kloc == 25) {
            v = bih[gunit] + bhh[gunit];        // bias row
        }
    } else {
        v = Whh[gunit * 64 + (ch - 1) * 32 + kloc];
    }
    const int gate = gunit >> 6;
    const float s = (gate == 2) ? K2E : -KE;
    wfrag[((ch * 16 + gt) * 64 + lane) * 8 + j] = f2bf(s * v);
}

#define CVTPK(D, A, B_)                                                      \
    asm("v_cvt_pk_bf16_f32 %0, %1, %2" : "=v"(D) : "v"(A), "v"(B_));

// LDS-only barrier: h exchange needs lgkmcnt drained, NOT vmcnt — msg
// prefetch loads stay in flight across the barrier.
#define BARRIER()                                                            \
    asm volatile("s_waitcnt lgkmcnt(0)\n\ts_barrier" ::: "memory");

// Load next msg slice as raw f32 (8 regs) from PTR; consumed 2 steps later.
#define LOADMSG(DST, PTR)                                                    \
    {                                                                        \
        const float* p_ = (PTR) + kq;                                        \
        if (kq < 24) {                                                       \
            _Pragma("unroll") for (int j = 0; j < 8; ++j) DST[j] = p_[j];    \
        } else {                                                             \
            DST[0] = p_[0]; DST[1] = 1.0f;   /* bias row k=25 */             \
            _Pragma("unroll") for (int j = 2; j < 8; ++j) DST[j] = 0.f;      \
        }                                                                    \
    }

#define CONVMSG(MB, MF)                                                      \
    {                                                                        \
        CVTPK(MB.u.x, MF[0], MF[1]) CVTPK(MB.u.y, MF[2], MF[3])              \
        CVTPK(MB.u.z, MF[4], MF[5]) CVTPK(MB.u.w, MF[6], MF[7])              \
    }

// One LSTM step. MF holds step S's msg (f32), refilled with step S+2's.
#define STEP(S, CURB, NXTB, MF)                                              \
    {                                                                        \
        bf16x8 bh0, bh1;                                                     \
        {                                                                    \
            int o0_ = (l16 * 128 + 0 * 64 + lq * 16) ^ swz;                  \
            int o1_ = (l16 * 128 + 1 * 64 + lq * 16) ^ swz;                  \
            bh0 = *(const bf16x8*)((CURB) + o0_);                            \
            bh1 = *(const bf16x8*)((CURB) + o1_);                            \
        }                                                                    \
        U16B mc_;                                                            \
        CONVMSG(mc_, MF)                                                     \
        if ((S) < 62) { LOADMSG(MF, mp) }                                    \
        mp += 25;                                                            \
        f32x4 acc[4];                                                        \
        _Pragma("unroll") for (int i = 0; i < 4; ++i)                        \
            acc[i] = __builtin_amdgcn_mfma_f32_16x16x32_bf16(                \
                w[0][i], mc_.v, z4, 0, 0, 0);                                \
        _Pragma("unroll") for (int i = 0; i < 4; ++i)                        \
            acc[i] = __builtin_amdgcn_mfma_f32_16x16x32_bf16(                \
                w[1][i], bh0, acc[i], 0, 0, 0);                              \
        _Pragma("unroll") for (int i = 0; i < 4; ++i)                        \
            acc[i] = __builtin_amdgcn_mfma_f32_16x16x32_bf16(                \
                w[2][i], bh1, acc[i], 0, 0, 0);                              \
        unsigned hw0_, hw1_;                                                 \
        _Pragma("unroll") for (int pp = 0; pp < 2; ++pp) {                   \
            f32x2 ai, af, ag, ao;                                            \
            ai[0] = acc[0][2*pp]; ai[1] = acc[0][2*pp+1];                    \
            af[0] = acc[1][2*pp]; af[1] = acc[1][2*pp+1];                    \
            ag[0] = acc[2][2*pp]; ag[1] = acc[2][2*pp+1];                    \
            ao[0] = acc[3][2*pp]; ao[1] = acc[3][2*pp+1];                    \
            f32x2 ti, tf_, tg, to_;                                          \
            ti[0]  = __builtin_amdgcn_exp2f(ai[0]);                          \
            ti[1]  = __builtin_amdgcn_exp2f(ai[1]);                          \
            tf_[0] = __builtin_amdgcn_exp2f(af[0]);                          \
            tf_[1] = __builtin_amdgcn_exp2f(af[1]);                          \
            to_[0] = __builtin_amdgcn_exp2f(ao[0]);                          \
            to_[1] = __builtin_amdgcn_exp2f(ao[1]);                          \
            tg[0]  = __builtin_amdgcn_exp2f(-fabsf(ag[0]));                  \
            tg[1]  = __builtin_amdgcn_exp2f(-fabsf(ag[1]));                  \
            f32x2 F_ = tf_ + 1.f;                                            \
            f32x2 P_ = (ti + 1.f) * (tg + 1.f);                              \
            f32x2 D_ = P_ * F_;                                              \
            f32x2 G_ = (1.f - tg) * F_;                                      \
            G_[0] = copysignf(G_[0], ag[0]);                                 \
            G_[1] = copysignf(G_[1], ag[1]);                                 \
            f32x2 num_ = c2[pp] * P_ + G_;                                   \
            f32x2 rD_;                                                       \
            rD_[0] = __builtin_amdgcn_rcpf(D_[0]);                           \
            rD_[1] = __builtin_amdgcn_rcpf(D_[1]);                           \
            f32x2 cn_ = num_ * rD_;                                          \
            c2[pp] = cn_;                                                    \
            f32x2 kc_ = cn_ * K2E;                                           \
            f32x2 tc_;                                                       \
            tc_[0] = __builtin_amdgcn_exp2f(-fabsf(kc_[0]));                 \
            tc_[1] = __builtin_amdgcn_exp2f(-fabsf(kc_[1]));                 \
            f32x2 D2_ = (to_ + 1.f) * (tc_ + 1.f);                           \
            f32x2 rD2_;                                                      \
            rD2_[0] = __builtin_amdgcn_rcpf(D2_[0]);                         \
            rD2_[1] = __builtin_amdgcn_rcpf(D2_[1]);                         \
            f32x2 ot_ = (1.f - tc_) * rD2_;                                  \
            float h0_ = copysignf(ot_[0], cn_[0]);                           \
            float h1_ = copysignf(ot_[1], cn_[1]);                           \
            if (pp == 0) { CVTPK(hw0_, h0_, h1_) }                           \
            else         { CVTPK(hw1_, h0_, h1_) }                           \
        }                                                                    \
        *(uint2*)((NXTB) + offw) = make_uint2(hw0_, hw1_);                   \
        BARRIER()                                                            \
    }

__global__ __launch_bounds__(256, 4) void lstm_mfma(
    const float* __restrict__ msgs,
    const unsigned short* __restrict__ wfrag,
    const float* __restrict__ fcw,
    const float* __restrict__ fcb,
    float* __restrict__ out)
{
    // double-buffered h: buf = h[16 brows][64 units] bf16 = 2KB, x2
    __shared__ __align__(16) char lds[4096];

    const int tid  = threadIdx.x;
    const int lane = tid & 63;
    const int cg   = __builtin_amdgcn_readfirstlane(tid >> 6); // 0..3 (SGPR)
    const int l16  = lane & 15;                 // batch row within tile
    const int lq   = lane >> 4;                 // k-quad / unit-quad
    const int row0 = blockIdx.x * 16;
    const int kq   = lq * 8;                    // k base within chunk

    // weight A-fragments in VGPRs: gate i -> tile 4i+cg, 3 chunks (48 regs)
    bf16x8 w[3][4];
    #pragma unroll
    for (int ch = 0; ch < 3; ++ch)
        #pragma unroll
        for (int i = 0; i < 4; ++i)
            w[ch][i] = *(const bf16x8*)(wfrag + ((ch * 16 + 4 * i + cg) * 64 + lane) * 8);

    // zero h buffer 0 (2KB)
    for (int idx = tid; idx < 512; idx += 256) ((unsigned int*)lds)[idx] = 0u;

    // persistent zero C-operand for the first MFMA of each chain
    const f32x4 z4 = (f32x4){0.f, 0.f, 0.f, 0.f};

    f32x2 c2[2];
    c2[0] = (f32x2){0.f, 0.f};
    c2[1] = (f32x2){0.f, 0.f};

    const float* mrow = msgs + (long)(row0 + l16) * 1600;
    const float* mp   = mrow + 50;              // next msg slice to prefetch (s=2)
    const int swz  = (l16 & 7) << 4;
    // this thread writes h[brow=l16][units 16cg+4lq .. +3] -> 8B
    const int offw = (l16 * 128 + cg * 32 + lq * 8) ^ swz;

    float mfA[8], mfB[8];
    LOADMSG(mfA, mrow)
    LOADMSG(mfB, mrow + 25)
    __syncthreads();   // one-time full barrier (zeroed LDS visible)

    char* b0 = (char*)lds;
    char* b1 = b0 + 2048;
    for (int s2 = 0; s2 < 64; s2 += 2) {
        STEP(s2,     b0, b1, mfA)
        STEP(s2 + 1, b1, b0, mfB)
    }

    // final h in b0 as h[brow][unit]. FC epilogue: thread -> (row, class)
    if (tid < 64) {
        const int r = tid >> 2, cls = tid & 3;
        if (cls < 3) {
            float a = fcb[cls];
            const int sw = (r & 7) << 4;
            #pragma unroll
            for (int u = 0; u < 64; ++u) {
                int off = (r * 128 + u * 2) ^ sw;
                float hv = bf2f(*(const unsigned short*)(b0 + off));
                a = fmaf(hv, fcw[cls * 64 + u], a);
            }
            out[(row0 + r) * 3 + cls] = a;
        }
    }
}

extern "C" void kernel_launch(void* const* d_in, const int* in_sizes, int n_in,
                              void* d_out, int out_size, void* d_ws, size_t ws_size,
                              hipStream_t stream) {
    const float* msgs = (const float*)d_in[0];
    const float* emb  = (const float*)d_in[1];
    const float* Wih  = (const float*)d_in[2];
    const float* Whh  = (const float*)d_in[3];
    const float* bih  = (const float*)d_in[4];
    const float* bhh  = (const float*)d_in[5];
    const float* fcw  = (const float*)d_in[6];
    const float* fcb  = (const float*)d_in[7];
    float* out = (float*)d_out;

    // ws: wfrag bf16[3*16*64*8] = 49152 B
    unsigned short* wfrag = (unsigned short*)d_ws;

    prep_kernel<<<48, 512, 0, stream>>>(emb, Wih, Whh, bih, bhh, wfrag);
    lstm_mfma<<<16384 / 16, 256, 0, stream>>>(msgs, wfrag, fcw, fcb, out);
}